// Round 7
// baseline (152.773 us; speedup 1.0000x reference)
//
#include <hip/hip_runtime.h>

// B=16, V=20000, D=H=256. Output fp32 [16][20000].
// prep: repack Wa/W1[D:] to MFMA B-frag bf16; patient path -> EpT[h][b]=exp2(C*ph)
// tile: 1250 blocks x ONE wave, 16 v-rows each. Zero cross-wave coupling:
//       direct global->A-frag loads, GEMM1 (128 MFMA), in-wave row-LN,
//       wave-local LDS transpose, GEMM2, Ea=exp2 in place, contraction with
//       Ep float4 loads straight from L1-resident EpT (16 KB), per-pass
//       in-wave butterfly reduce -> scores + stats. No __syncthreads except
//       one lgkm fence for the LDS transpose.
// final: stats reduce + LN over V.
// tanh(z)=1-2/(1+e^{2z}); constants cancel in final LN (shift-invariant):
// out = -2*(S-mean_S)*rsqrt(4*var_S+eps)*g_pred + b_pred, S = sum_h W2/(1+Ep*Ea).

typedef unsigned short ushort_t;
typedef __attribute__((ext_vector_type(8))) short short8;
typedef __attribute__((ext_vector_type(4))) float floatx4;

#define C2F 2.8853900817779268f  // 2*log2(e)
#define V_N 20000
#define NBLK 1250                // V_N / 16

__device__ __forceinline__ ushort_t f2bf(float f) {
    unsigned int u = __builtin_bit_cast(unsigned int, f);
    u += 0x7FFFu + ((u >> 16) & 1u);   // RNE
    return (ushort_t)(u >> 16);
}
__device__ __forceinline__ float exp2_fast(float x) { return __builtin_amdgcn_exp2f(x); }
__device__ __forceinline__ float rcp_fast(float x)  { return __builtin_amdgcn_rcpf(x); }

// ---------------------------------------------------------------------------
// prep: blocks 0..15 repack Wa / W1[D:] into B-frag order (validated R1-R6):
//   elem ((s*16+T)*64+l)*8+j = src[(s*32+(l>>4)*8+j)*256 + T*16+(l&15)]
// blocks 16..31: patient path, one block per b -> EpT[h*16+b]
// ---------------------------------------------------------------------------
__global__ __launch_bounds__(1024) void prep_kernel(
    const float* __restrict__ patient_emb, const float* __restrict__ Wp,
    const float* __restrict__ bp, const float* __restrict__ gp,
    const float* __restrict__ betap, const float* __restrict__ Wa,
    const float* __restrict__ W1, ushort_t* __restrict__ pWa,
    ushort_t* __restrict__ pW1b, float* __restrict__ EpT)
{
    const int blk = blockIdx.x;
    const int tid = threadIdx.x;
    __shared__ float peL[256];
    __shared__ float pL[256];
    __shared__ float part[4][256];
    __shared__ float red[8];

    if (blk < 16) {
        int slot = blk * 1024 + tid;        // 16384 slots = 2 matrices * 8192
        int matrix = slot >> 13;
        int rest = slot & 8191;
        int s = rest >> 10, T = (rest >> 6) & 15, l = rest & 63;
        const float* src = matrix ? (W1 + 256 * 256) : Wa;
        ushort_t* dst = matrix ? pW1b : pWa;
        int kbase = s * 32 + ((l >> 4) << 3);
        int nn = (T << 4) + (l & 15);
        short8 t;
        #pragma unroll
        for (int j = 0; j < 8; ++j)
            t[j] = (short)f2bf(src[(kbase + j) * 256 + nn]);
        *(short8*)(dst + rest * 8) = t;
        return;
    }

    const int b = blk - 16;
    const int j = tid & 255, pq = tid >> 8;   // 4-way K split
    if (tid < 256) peL[tid] = patient_emb[b * 256 + tid];
    __syncthreads();
    float a0 = 0.f;
    #pragma unroll 8
    for (int dd = 0; dd < 64; ++dd) {
        int d = pq * 64 + dd;
        a0 += peL[d] * Wp[d * 256 + j];
    }
    part[pq][j] = a0;
    __syncthreads();
    float x = 0.f;
    if (tid < 256) {
        x = part[0][j] + part[1][j] + part[2][j] + part[3][j] + bp[j];
        float s1 = x, s2 = x * x;
        #pragma unroll
        for (int off = 32; off; off >>= 1) {
            s1 += __shfl_xor(s1, off);
            s2 += __shfl_xor(s2, off);
        }
        int wv = tid >> 6;
        if ((tid & 63) == 0) { red[wv * 2] = s1; red[wv * 2 + 1] = s2; }
    }
    __syncthreads();
    if (tid < 256) {
        float s1 = red[0] + red[2] + red[4] + red[6];
        float s2 = red[1] + red[3] + red[5] + red[7];
        float mean = s1 * (1.f / 256.f);
        float var  = s2 * (1.f / 256.f) - mean * mean;
        float rstd = rsqrtf(var + 1e-5f);
        pL[tid] = (x - mean) * rstd * gp[tid] + betap[tid];
    }
    __syncthreads();
    float a2 = 0.f;
    #pragma unroll 8
    for (int dd = 0; dd < 64; ++dd) {
        int d = pq * 64 + dd;
        a2 += pL[d] * W1[d * 256 + j];   // W1[:D]
    }
    part[pq][j] = a2;
    __syncthreads();
    if (tid < 256)
        EpT[tid * 16 + b] = exp2_fast(
            C2F * (part[0][tid] + part[1][tid] + part[2][tid] + part[3][tid]));
}

// ---------------------------------------------------------------------------
// tile: ONE wave per 16 v-rows, 1250 blocks. No cross-wave coupling.
// MFMA 16x16x32_bf16: A lane: A[m=lane&15][k=(lane>>4)*8+j]; C/D:
// D[(lane>>4)*4+r][lane&15]. GEMM2 A-tile in LDS frag order:
//   short8 slot (s*64 + q2*16 + row)*8+j  <->  A2[row][k=s*32+q2*8+j]
// ---------------------------------------------------------------------------
__global__ __launch_bounds__(64, 2) void tile_kernel(
    const float* __restrict__ atc4, const float* __restrict__ ba,
    const float* __restrict__ ga, const float* __restrict__ betaa,
    const float* __restrict__ b1, const float* __restrict__ W2,
    const ushort_t* __restrict__ pWa, const ushort_t* __restrict__ pW1b,
    const float* __restrict__ EpT, float* __restrict__ scores,
    float* __restrict__ s1g, float* __restrict__ s2g)
{
    __shared__ ushort_t Atile2[4096 + 128];   // 8.25 KB, frag order + slack

    const int lane = threadIdx.x;
    const int q = lane >> 4, n = lane & 15;
    const int v0 = blockIdx.x * 16;

    // ---- A fragments straight from global (validated R2): row n, k=s*32+q*8 ----
    short8 af[8];
    #pragma unroll
    for (int s = 0; s < 8; ++s) {
        const float* src = atc4 + (v0 + n) * 256 + s * 32 + q * 8;
        float4 f0 = *(const float4*)(src);
        float4 f1 = *(const float4*)(src + 4);
        short8 t;
        t[0] = (short)f2bf(f0.x); t[1] = (short)f2bf(f0.y);
        t[2] = (short)f2bf(f0.z); t[3] = (short)f2bf(f0.w);
        t[4] = (short)f2bf(f1.x); t[5] = (short)f2bf(f1.y);
        t[6] = (short)f2bf(f1.z); t[7] = (short)f2bf(f1.w);
        af[s] = t;
    }

    // ---- GEMM1: all 256 cols for this wave's 16 rows ----
    floatx4 acc[16];
    #pragma unroll
    for (int ni = 0; ni < 16; ++ni) acc[ni] = (floatx4){0.f, 0.f, 0.f, 0.f};
    #pragma unroll
    for (int s = 0; s < 8; ++s) {
        #pragma unroll
        for (int ni = 0; ni < 16; ++ni) {
            short8 bfv = *(const short8*)(pWa + ((s * 16 + ni) * 64 + lane) * 8);
            acc[ni] = __builtin_amdgcn_mfma_f32_16x16x32_bf16(af[s], bfv, acc[ni], 0, 0, 0);
        }
    }

    // ---- bias + row-LN stats fully in-wave (params inline from L1) ----
    float s1v[4] = {0, 0, 0, 0}, s2v[4] = {0, 0, 0, 0};
    #pragma unroll
    for (int ni = 0; ni < 16; ++ni) {
        float bav = ba[ni * 16 + n];
        #pragma unroll
        for (int r = 0; r < 4; ++r) {
            float x = acc[ni][r] + bav;
            acc[ni][r] = x;
            s1v[r] += x; s2v[r] += x * x;
        }
    }
    #pragma unroll
    for (int off = 1; off < 16; off <<= 1)
        #pragma unroll
        for (int r = 0; r < 4; ++r) {
            s1v[r] += __shfl_xor(s1v[r], off);
            s2v[r] += __shfl_xor(s2v[r], off);
        }
    float mean[4], rstd[4];
    #pragma unroll
    for (int r = 0; r < 4; ++r) {
        mean[r] = s1v[r] * (1.f / 256.f);
        float var = s2v[r] * (1.f / 256.f) - mean[r] * mean[r];
        rstd[r] = rsqrtf(var + 1e-5f);
    }

    // ---- LN apply; scatter bf16 into Atile2 in GEMM2 A-frag order ----
    // col = ni*16+n -> s2=ni>>1, q2=(ni&1)*2+(n>>3), j=n&7; row=q*4+r
    #pragma unroll
    for (int ni = 0; ni < 16; ++ni) {
        float gav = ga[ni * 16 + n], bev = betaa[ni * 16 + n];
        #pragma unroll
        for (int r = 0; r < 4; ++r) {
            float xv = (acc[ni][r] - mean[r]) * rstd[r] * gav + bev;
            int addr = ((ni >> 1) * 64 + ((ni & 1) * 2 + (n >> 3)) * 16 +
                        (q * 4 + r)) * 8 + (n & 7);
            Atile2[addr] = f2bf(xv);
        }
    }
    __syncthreads();   // single wave: just the lgkm drain for write->read

    // ---- GEMM2 ----
    floatx4 acc2[16];
    #pragma unroll
    for (int ni = 0; ni < 16; ++ni) acc2[ni] = (floatx4){0.f, 0.f, 0.f, 0.f};
    #pragma unroll
    for (int s = 0; s < 8; ++s) {
        short8 a2 = ((const short8*)Atile2)[s * 64 + lane];
        #pragma unroll
        for (int ni = 0; ni < 16; ++ni) {
            short8 bfv = *(const short8*)(pW1b + ((s * 16 + ni) * 64 + lane) * 8);
            acc2[ni] = __builtin_amdgcn_mfma_f32_16x16x32_bf16(a2, bfv, acc2[ni], 0, 0, 0);
        }
    }

    // ---- Ea = exp2(C*(ah+b1)) in place ----
    #pragma unroll
    for (int ni = 0; ni < 16; ++ni) {
        float b1v = C2F * b1[ni * 16 + n];
        #pragma unroll
        for (int r = 0; r < 4; ++r)
            acc2[ni][r] = exp2_fast(fmaf(C2F, acc2[ni][r], b1v));
    }

    // ---- contraction: 4 serial passes of 4 batch rows; Ep from L1 ----
    const int blk = blockIdx.x;
    #pragma unroll 1
    for (int p = 0; p < 4; ++p) {
        float accs[4][4];
        #pragma unroll
        for (int bb = 0; bb < 4; ++bb)
            #pragma unroll
            for (int r = 0; r < 4; ++r) accs[bb][r] = 0.f;
        #pragma unroll
        for (int ni = 0; ni < 16; ++ni) {
            float w2v = W2[ni * 16 + n];
            float4 e0 = *(const float4*)(EpT + (ni * 16 + n) * 16 + p * 4);
            float ep[4] = {e0.x, e0.y, e0.z, e0.w};
            #pragma unroll
            for (int bb = 0; bb < 4; ++bb)
                #pragma unroll
                for (int r = 0; r < 4; ++r)
                    accs[bb][r] += w2v * rcp_fast(fmaf(ep[bb], acc2[ni][r], 1.f));
        }
        // butterfly reduce-scatter over 16 n-lanes (validated R5): b = p*4+(n&3)
        float t2v[2][4], t1[4];
        {
            int hb = n & 1;
            #pragma unroll
            for (int p2 = 0; p2 < 2; ++p2)
                #pragma unroll
                for (int r = 0; r < 4; ++r) {
                    float keep = hb ? accs[2 * p2 + 1][r] : accs[2 * p2][r];
                    float send = hb ? accs[2 * p2][r] : accs[2 * p2 + 1][r];
                    t2v[p2][r] = keep + __shfl_xor(send, 1);
                }
            hb = (n >> 1) & 1;
            #pragma unroll
            for (int r = 0; r < 4; ++r) {
                float keep = hb ? t2v[1][r] : t2v[0][r];
                float send = hb ? t2v[0][r] : t2v[1][r];
                t1[r] = keep + __shfl_xor(send, 2);
            }
            #pragma unroll
            for (int r = 0; r < 4; ++r) {
                t1[r] += __shfl_xor(t1[r], 4);
                t1[r] += __shfl_xor(t1[r], 8);
            }
        }
        // lane (q, n<4): t1[r] = S[b=p*4+n][v0+q*4+r] -> float4 store
        if (n < 4) {
            *(float4*)(scores + (p * 4 + n) * V_N + v0 + q * 4) =
                make_float4(t1[0], t1[1], t1[2], t1[3]);
        }
        // per-block stats: sum over this block's 16 v per b
        float ls1 = t1[0] + t1[1] + t1[2] + t1[3];
        float ls2 = t1[0] * t1[0] + t1[1] * t1[1] + t1[2] * t1[2] + t1[3] * t1[3];
        ls1 += __shfl_xor(ls1, 16); ls1 += __shfl_xor(ls1, 32);
        ls2 += __shfl_xor(ls2, 16); ls2 += __shfl_xor(ls2, 32);
        if (lane < 4) {
            s1g[(p * 4 + lane) * NBLK + blk] = ls1;
            s2g[(p * 4 + lane) * NBLK + blk] = ls2;
        }
    }
}

// ---------------------------------------------------------------------------
// final: grid (10 chunks, 16 b). Redundant cheap stats reduce per block, then
// out = -2*(S-mean)*rsqrt(4*var+eps)*g_pred + b_pred.
// ---------------------------------------------------------------------------
__global__ __launch_bounds__(256) void final_kernel(
    const float* __restrict__ scores, const float* __restrict__ s1g,
    const float* __restrict__ s2g, const float* __restrict__ g_pred,
    const float* __restrict__ b_pred, float* __restrict__ out)
{
    const int cx = blockIdx.x, b = blockIdx.y, tid = threadIdx.x;
    __shared__ float redL[8];
    float ls1 = 0.f, ls2 = 0.f;
    for (int i = tid; i < NBLK; i += 256) {
        ls1 += s1g[b * NBLK + i];
        ls2 += s2g[b * NBLK + i];
    }
    #pragma unroll
    for (int off = 32; off; off >>= 1) {
        ls1 += __shfl_xor(ls1, off);
        ls2 += __shfl_xor(ls2, off);
    }
    int w = tid >> 6;
    if ((tid & 63) == 0) { redL[w] = ls1; redL[4 + w] = ls2; }
    __syncthreads();
    float S1 = redL[0] + redL[1] + redL[2] + redL[3];
    float S2 = redL[4] + redL[5] + redL[6] + redL[7];
    float mean = S1 * (1.f / 20000.f);
    float var  = S2 * (1.f / 20000.f) - mean * mean;
    float k = -2.f * rsqrtf(4.f * var + 1e-5f);
    #pragma unroll
    for (int i = 0; i < 8; ++i) {
        int off = i * 256 + tid;
        if (off < 2000) {
            int v = cx * 2000 + off;
            float S = scores[b * V_N + v];
            out[b * V_N + v] = (S - mean) * k * g_pred[v] + b_pred[v];
        }
    }
}

extern "C" void kernel_launch(void* const* d_in, const int* in_sizes, int n_in,
                              void* d_out, int out_size, void* d_ws, size_t ws_size,
                              hipStream_t stream)
{
    const float* patient_emb = (const float*)d_in[0];
    const float* atc4        = (const float*)d_in[1];
    const float* Wp     = (const float*)d_in[2];
    const float* bp     = (const float*)d_in[3];
    const float* gp     = (const float*)d_in[4];
    const float* betap  = (const float*)d_in[5];
    const float* Wa     = (const float*)d_in[6];
    const float* ba     = (const float*)d_in[7];
    const float* ga     = (const float*)d_in[8];
    const float* betaa  = (const float*)d_in[9];
    const float* W1     = (const float*)d_in[10];
    const float* b1     = (const float*)d_in[11];
    const float* W2     = (const float*)d_in[12];
    // d_in[13] = b2: constant, cancels under the final LN
    const float* g_pred = (const float*)d_in[14];
    const float* b_pred = (const float*)d_in[15];

    char* ws = (char*)d_ws;
    float*    EpT    = (float*)(ws);                 //  16384 B
    ushort_t* pWa    = (ushort_t*)(ws + 16384);      // 131072 B
    ushort_t* pW1b   = (ushort_t*)(ws + 147456);     // 131072 B
    float*    scores = (float*)(ws + 278528);        // 1280000 B
    float*    s1g    = (float*)(ws + 1558528);       //  80000 B
    float*    s2g    = (float*)(ws + 1638528);       //  80000 B
    float*    out    = (float*)d_out;

    prep_kernel<<<32, 1024, 0, stream>>>(patient_emb, Wp, bp, gp, betap,
                                         Wa, W1, pWa, pW1b, EpT);
    tile_kernel<<<NBLK, 64, 0, stream>>>(atc4, ba, ga, betaa, b1, W2,
                                         pWa, pW1b, EpT, scores, s1g, s2g);
    final_kernel<<<dim3(10, 16), 256, 0, stream>>>(scores, s1g, s2g,
                                                   g_pred, b_pred, out);
}

// Round 8
// 134.173 us; speedup vs baseline: 1.1386x; 1.1386x over previous
//
#include <hip/hip_runtime.h>

// B=16, V=20000, D=H=256. Output fp32 [16][20000].
// prep:  repack Wa/W1[D:] to MFMA B-frag bf16; patient path -> EpT[h][b]=exp2(C*ph)
// mega:  1250 blocks x 4 waves, 16 v-rows/block, h split across waves (64 each).
//        GEMM1 (bf16 MFMA) + cross-wave row-LN -> frag-order LDS -> GEMM2 ->
//        Ea=exp2 in-place -> 4 contraction passes (Ep direct from L1-resident
//        EpT, params inline) -> single-barrier batched tail.
// final: stats reduce + LN over V.
// tanh(z)=1-2/(1+e^{2z}); constants cancel in final LN (shift-invariant):
// out = -2*(S-mean_S)*rsqrt(4*var_S+eps)*g_pred + b_pred, S = sum_h W2/(1+Ep*Ea).

typedef unsigned short ushort_t;
typedef __attribute__((ext_vector_type(8))) short short8;
typedef __attribute__((ext_vector_type(4))) float floatx4;

#define C2F 2.8853900817779268f  // 2*log2(e)
#define V_N 20000
#define NBLK 1250                // V_N / 16

__device__ __forceinline__ ushort_t f2bf(float f) {
    unsigned int u = __builtin_bit_cast(unsigned int, f);
    u += 0x7FFFu + ((u >> 16) & 1u);   // RNE
    return (ushort_t)(u >> 16);
}
__device__ __forceinline__ float exp2_fast(float x) { return __builtin_amdgcn_exp2f(x); }
__device__ __forceinline__ float rcp_fast(float x)  { return __builtin_amdgcn_rcpf(x); }

// ---------------------------------------------------------------------------
// prep: blocks 0..15 repack Wa / W1[D:] into B-frag order (validated R1-R7):
//   elem ((s*16+T)*64+l)*8+j = src[(s*32+(l>>4)*8+j)*256 + T*16+(l&15)]
// blocks 16..31: patient path, one block per b -> EpT[h*16+b]
// ---------------------------------------------------------------------------
__global__ __launch_bounds__(1024) void prep_kernel(
    const float* __restrict__ patient_emb, const float* __restrict__ Wp,
    const float* __restrict__ bp, const float* __restrict__ gp,
    const float* __restrict__ betap, const float* __restrict__ Wa,
    const float* __restrict__ W1, ushort_t* __restrict__ pWa,
    ushort_t* __restrict__ pW1b, float* __restrict__ EpT)
{
    const int blk = blockIdx.x;
    const int tid = threadIdx.x;
    __shared__ float peL[256];
    __shared__ float pL[256];
    __shared__ float part[4][256];
    __shared__ float red[8];

    if (blk < 16) {
        int slot = blk * 1024 + tid;        // 16384 slots = 2 matrices * 8192
        int matrix = slot >> 13;
        int rest = slot & 8191;
        int s = rest >> 10, T = (rest >> 6) & 15, l = rest & 63;
        const float* src = matrix ? (W1 + 256 * 256) : Wa;
        ushort_t* dst = matrix ? pW1b : pWa;
        int kbase = s * 32 + ((l >> 4) << 3);
        int nn = (T << 4) + (l & 15);
        short8 t;
        #pragma unroll
        for (int j = 0; j < 8; ++j)
            t[j] = (short)f2bf(src[(kbase + j) * 256 + nn]);
        *(short8*)(dst + rest * 8) = t;
        return;
    }

    const int b = blk - 16;
    const int j = tid & 255, pq = tid >> 8;   // 4-way K split
    if (tid < 256) peL[tid] = patient_emb[b * 256 + tid];
    __syncthreads();
    float a0 = 0.f;
    #pragma unroll 8
    for (int dd = 0; dd < 64; ++dd) {
        int d = pq * 64 + dd;
        a0 += peL[d] * Wp[d * 256 + j];
    }
    part[pq][j] = a0;
    __syncthreads();
    float x = 0.f;
    if (tid < 256) {
        x = part[0][j] + part[1][j] + part[2][j] + part[3][j] + bp[j];
        float s1 = x, s2 = x * x;
        #pragma unroll
        for (int off = 32; off; off >>= 1) {
            s1 += __shfl_xor(s1, off);
            s2 += __shfl_xor(s2, off);
        }
        int wv = tid >> 6;
        if ((tid & 63) == 0) { red[wv * 2] = s1; red[wv * 2 + 1] = s2; }
    }
    __syncthreads();
    if (tid < 256) {
        float s1 = red[0] + red[2] + red[4] + red[6];
        float s2 = red[1] + red[3] + red[5] + red[7];
        float mean = s1 * (1.f / 256.f);
        float var  = s2 * (1.f / 256.f) - mean * mean;
        float rstd = rsqrtf(var + 1e-5f);
        pL[tid] = (x - mean) * rstd * gp[tid] + betap[tid];
    }
    __syncthreads();
    float a2 = 0.f;
    #pragma unroll 8
    for (int dd = 0; dd < 64; ++dd) {
        int d = pq * 64 + dd;
        a2 += pL[d] * W1[d * 256 + j];   // W1[:D]
    }
    part[pq][j] = a2;
    __syncthreads();
    if (tid < 256)
        EpT[tid * 16 + b] = exp2_fast(
            C2F * (part[0][tid] + part[1][tid] + part[2][tid] + part[3][tid]));
}

// ---------------------------------------------------------------------------
// mega: 256 threads (4 waves), 16 v-rows. Wave w owns h/d cols [64w,64w+64).
// MFMA 16x16x32_bf16: A lane: A[m=lane&15][k=(lane>>4)*8+j]; C/D:
// D[(lane>>4)*4+r][lane&15]. A tile in LDS in frag order:
//   short8 slot (s*64 + q*16 + row)*8+j  <->  A[row][k=s*32+q*8+j]
// launch_bounds(256,3): cap ~170 VGPR ((256,4) clamps to 64 -> spills, R4).
// R8: EpL LDS dropped (Ep read direct from EpT, R7-proven); params inline.
// ---------------------------------------------------------------------------
__global__ __launch_bounds__(256, 3) void mega_kernel(
    const float* __restrict__ atc4, const float* __restrict__ ba,
    const float* __restrict__ ga, const float* __restrict__ betaa,
    const float* __restrict__ b1, const float* __restrict__ W2,
    const ushort_t* __restrict__ pWa, const ushort_t* __restrict__ pW1b,
    const float* __restrict__ EpT, float* __restrict__ scores,
    float* __restrict__ s1g, float* __restrict__ s2g)
{
    __shared__ ushort_t AtileF[4096];      // 8 KB, frag order (8 s x 64 lane x 8)
    __shared__ float statsP[4][16][2];
    __shared__ float statsF[16][2];
    __shared__ float redbuf[16][4][17];    // [bg][w][v(+1 pad)] - batched tail

    const int tid = threadIdx.x;
    const int w = tid >> 6, lane = tid & 63;
    const int q = lane >> 4, n = lane & 15;
    const int v0 = blockIdx.x * 16;

    // ---- stage A tile (16 rows x 256 cols) straight into frag order ----
    {
        const int row = tid >> 4;
        const int kb = (tid & 15) * 16;
        const float* srcp = atc4 + (v0 + row) * 256 + kb;
        #pragma unroll
        for (int i = 0; i < 4; ++i) {
            int k = kb + i * 4;
            float4 f = *(const float4*)(srcp + i * 4);
            ushort4 usv = make_ushort4(f2bf(f.x), f2bf(f.y), f2bf(f.z), f2bf(f.w));
            int addr = (((k >> 5) * 64) + (((k >> 3) & 3) * 16) + row) * 8 + (k & 7);
            *(ushort4*)(AtileF + addr) = usv;
        }
    }
    __syncthreads();

    // ---- GEMM1: cols w*64 + ni*16 + n ----
    floatx4 acc[4];
    #pragma unroll
    for (int ni = 0; ni < 4; ++ni) acc[ni] = (floatx4){0.f, 0.f, 0.f, 0.f};
    #pragma unroll
    for (int s = 0; s < 8; ++s) {
        short8 a0 = ((const short8*)AtileF)[s * 64 + lane];
        #pragma unroll
        for (int ni = 0; ni < 4; ++ni) {
            short8 bfv = *(const short8*)(pWa + ((s * 16 + w * 4 + ni) * 64 + lane) * 8);
            acc[ni] = __builtin_amdgcn_mfma_f32_16x16x32_bf16(a0, bfv, acc[ni], 0, 0, 0);
        }
    }

    // ---- bias + partial LN stats (params inline from L1) ----
    float s1v[4] = {0, 0, 0, 0}, s2v[4] = {0, 0, 0, 0};
    #pragma unroll
    for (int ni = 0; ni < 4; ++ni) {
        float bav = ba[w * 64 + ni * 16 + n];
        #pragma unroll
        for (int r = 0; r < 4; ++r) {
            float x = acc[ni][r] + bav;
            acc[ni][r] = x;
            s1v[r] += x; s2v[r] += x * x;
        }
    }
    #pragma unroll
    for (int off = 1; off < 16; off <<= 1)
        #pragma unroll
        for (int r = 0; r < 4; ++r) {
            s1v[r] += __shfl_xor(s1v[r], off);
            s2v[r] += __shfl_xor(s2v[r], off);
        }
    if (n == 0) {
        #pragma unroll
        for (int r = 0; r < 4; ++r) {
            statsP[w][q * 4 + r][0] = s1v[r];
            statsP[w][q * 4 + r][1] = s2v[r];
        }
    }
    __syncthreads();
    if (tid < 16) {
        float m1 = statsP[0][tid][0] + statsP[1][tid][0] + statsP[2][tid][0] + statsP[3][tid][0];
        float m2 = statsP[0][tid][1] + statsP[1][tid][1] + statsP[2][tid][1] + statsP[3][tid][1];
        float mean = m1 * (1.f / 256.f);
        float var  = m2 * (1.f / 256.f) - mean * mean;
        statsF[tid][0] = mean;
        statsF[tid][1] = rsqrtf(var + 1e-5f);
    }
    __syncthreads();

    // ---- LN apply (ga/betaa inline); scatter bf16 back into AtileF ----
    #pragma unroll
    for (int ni = 0; ni < 4; ++ni) {
        float gav = ga[w * 64 + ni * 16 + n];
        float bev = betaa[w * 64 + ni * 16 + n];
        #pragma unroll
        for (int r = 0; r < 4; ++r) {
            int row = q * 4 + r;
            float xv = (acc[ni][r] - statsF[row][0]) * statsF[row][1] * gav + bev;
            int addr = ((w * 2 + (ni >> 1)) * 64 +
                        ((ni & 1) * 2 + (n >> 3)) * 16 + row) * 8 + (n & 7);
            AtileF[addr] = f2bf(xv);
        }
    }
    __syncthreads();

    // ---- GEMM2 ----
    floatx4 acc2[4];
    #pragma unroll
    for (int ni = 0; ni < 4; ++ni) acc2[ni] = (floatx4){0.f, 0.f, 0.f, 0.f};
    #pragma unroll
    for (int s = 0; s < 8; ++s) {
        short8 a0 = ((const short8*)AtileF)[s * 64 + lane];
        #pragma unroll
        for (int ni = 0; ni < 4; ++ni) {
            short8 bfv = *(const short8*)(pW1b + ((s * 16 + w * 4 + ni) * 64 + lane) * 8);
            acc2[ni] = __builtin_amdgcn_mfma_f32_16x16x32_bf16(a0, bfv, acc2[ni], 0, 0, 0);
        }
    }

    // ---- Ea = exp2(C*(ah + b1)) IN PLACE (b1 inline) ----
    #pragma unroll
    for (int ni = 0; ni < 4; ++ni) {
        float b1v = C2F * b1[w * 64 + ni * 16 + n];
        #pragma unroll
        for (int r = 0; r < 4; ++r)
            acc2[ni][r] = exp2_fast(fmaf(C2F, acc2[ni][r], b1v));
    }

    // ---- contraction: 4 serial passes of 4 batch rows; Ep direct from EpT ----
    #pragma unroll 1
    for (int p = 0; p < 4; ++p) {
        float accs[4][4];
        #pragma unroll
        for (int bb = 0; bb < 4; ++bb)
            #pragma unroll
            for (int r = 0; r < 4; ++r) accs[bb][r] = 0.f;
        #pragma unroll
        for (int ni = 0; ni < 4; ++ni) {
            int col = w * 64 + ni * 16 + n;
            float w2v = W2[col];
            float4 e0 = *(const float4*)(EpT + col * 16 + p * 4);
            float ep[4] = {e0.x, e0.y, e0.z, e0.w};
            #pragma unroll
            for (int bb = 0; bb < 4; ++bb)
                #pragma unroll
                for (int r = 0; r < 4; ++r)
                    accs[bb][r] += w2v * rcp_fast(fmaf(ep[bb], acc2[ni][r], 1.f));
        }
        // butterfly reduce-scatter over 16 n-lanes: lane ends with b = p*4+(n&3)
        float t2v[2][4], t1[4];
        {
            int hb = n & 1;
            #pragma unroll
            for (int p2 = 0; p2 < 2; ++p2)
                #pragma unroll
                for (int r = 0; r < 4; ++r) {
                    float keep = hb ? accs[2 * p2 + 1][r] : accs[2 * p2][r];
                    float send = hb ? accs[2 * p2][r] : accs[2 * p2 + 1][r];
                    t2v[p2][r] = keep + __shfl_xor(send, 1);
                }
            hb = (n >> 1) & 1;
            #pragma unroll
            for (int r = 0; r < 4; ++r) {
                float keep = hb ? t2v[1][r] : t2v[0][r];
                float send = hb ? t2v[0][r] : t2v[1][r];
                t1[r] = keep + __shfl_xor(send, 2);
            }
            #pragma unroll
            for (int r = 0; r < 4; ++r) {
                t1[r] += __shfl_xor(t1[r], 4);
                t1[r] += __shfl_xor(t1[r], 8);
            }
        }
        if (n < 4) {
            #pragma unroll
            for (int r = 0; r < 4; ++r)
                redbuf[p * 4 + n][w][q * 4 + r] = t1[r];
        }
    }
    __syncthreads();   // ONE barrier for the whole batched tail
    {
        int bb = tid >> 4, v = tid & 15;   // all 256 threads: 16 b x 16 v
        float S = redbuf[bb][0][v] + redbuf[bb][1][v] +
                  redbuf[bb][2][v] + redbuf[bb][3][v];
        scores[bb * V_N + v0 + v] = S;
        float ls1 = S, ls2 = S * S;
        #pragma unroll
        for (int off = 1; off < 16; off <<= 1) {
            ls1 += __shfl_xor(ls1, off);
            ls2 += __shfl_xor(ls2, off);
        }
        if ((tid & 15) == 0) {
            s1g[bb * NBLK + blockIdx.x] = ls1;
            s2g[bb * NBLK + blockIdx.x] = ls2;
        }
    }
}

// ---------------------------------------------------------------------------
// final: grid (10 chunks, 16 b). Redundant cheap stats reduce per block, then
// out = -2*(S-mean)*rsqrt(4*var+eps)*g_pred + b_pred.
// ---------------------------------------------------------------------------
__global__ __launch_bounds__(256) void final_kernel(
    const float* __restrict__ scores, const float* __restrict__ s1g,
    const float* __restrict__ s2g, const float* __restrict__ g_pred,
    const float* __restrict__ b_pred, float* __restrict__ out)
{
    const int cx = blockIdx.x, b = blockIdx.y, tid = threadIdx.x;
    __shared__ float redL[8];
    float ls1 = 0.f, ls2 = 0.f;
    for (int i = tid; i < NBLK; i += 256) {
        ls1 += s1g[b * NBLK + i];
        ls2 += s2g[b * NBLK + i];
    }
    #pragma unroll
    for (int off = 32; off; off >>= 1) {
        ls1 += __shfl_xor(ls1, off);
        ls2 += __shfl_xor(ls2, off);
    }
    int w = tid >> 6;
    if ((tid & 63) == 0) { redL[w] = ls1; redL[4 + w] = ls2; }
    __syncthreads();
    float S1 = redL[0] + redL[1] + redL[2] + redL[3];
    float S2 = redL[4] + redL[5] + redL[6] + redL[7];
    float mean = S1 * (1.f / 20000.f);
    float var  = S2 * (1.f / 20000.f) - mean * mean;
    float k = -2.f * rsqrtf(4.f * var + 1e-5f);
    #pragma unroll
    for (int i = 0; i < 8; ++i) {
        int off = i * 256 + tid;
        if (off < 2000) {
            int v = cx * 2000 + off;
            float S = scores[b * V_N + v];
            out[b * V_N + v] = (S - mean) * k * g_pred[v] + b_pred[v];
        }
    }
}

extern "C" void kernel_launch(void* const* d_in, const int* in_sizes, int n_in,
                              void* d_out, int out_size, void* d_ws, size_t ws_size,
                              hipStream_t stream)
{
    const float* patient_emb = (const float*)d_in[0];
    const float* atc4        = (const float*)d_in[1];
    const float* Wp     = (const float*)d_in[2];
    const float* bp     = (const float*)d_in[3];
    const float* gp     = (const float*)d_in[4];
    const float* betap  = (const float*)d_in[5];
    const float* Wa     = (const float*)d_in[6];
    const float* ba     = (const float*)d_in[7];
    const float* ga     = (const float*)d_in[8];
    const float* betaa  = (const float*)d_in[9];
    const float* W1     = (const float*)d_in[10];
    const float* b1     = (const float*)d_in[11];
    const float* W2     = (const float*)d_in[12];
    // d_in[13] = b2: constant, cancels under the final LN
    const float* g_pred = (const float*)d_in[14];
    const float* b_pred = (const float*)d_in[15];

    char* ws = (char*)d_ws;
    float*    EpT    = (float*)(ws);                 //  16384 B
    ushort_t* pWa    = (ushort_t*)(ws + 16384);      // 131072 B
    ushort_t* pW1b   = (ushort_t*)(ws + 147456);     // 131072 B
    float*    scores = (float*)(ws + 278528);        // 1280000 B
    float*    s1g    = (float*)(ws + 1558528);       //  80000 B
    float*    s2g    = (float*)(ws + 1638528);       //  80000 B
    float*    out    = (float*)d_out;

    prep_kernel<<<32, 1024, 0, stream>>>(patient_emb, Wp, bp, gp, betap,
                                         Wa, W1, pWa, pW1b, EpT);
    mega_kernel<<<NBLK, 256, 0, stream>>>(atc4, ba, ga, betaa, b1, W2,
                                          pWa, pW1b, EpT, scores, s1g, s2g);
    final_kernel<<<dim3(10, 16), 256, 0, stream>>>(scores, s1g, s2g,
                                                   g_pred, b_pred, out);
}

// Round 9
// 133.547 us; speedup vs baseline: 1.1440x; 1.0047x over previous
//
#include <hip/hip_runtime.h>

// B=16, V=20000, D=H=256. Output fp32 [16][20000].
// prep:  repack Wa/W1[D:] to MFMA B-frag bf16; patient path -> EpT[h][b]=exp2(C*ph)
// mega:  1250 blocks x 4 waves, 16 v-rows/block, h split across waves (64 each).
//        GEMM1 (bf16 MFMA) + cross-wave row-LN (per-lane stats read, 4 barriers)
//        -> frag-order LDS -> GEMM2 -> Ea=exp2 in-place -> 4 contraction passes
//        (Ep software-pipelined from L1-resident EpT) -> single-barrier tail.
// final: stats reduce + LN over V.
// tanh(z)=1-2/(1+e^{2z}); constants cancel in final LN (shift-invariant):
// out = -2*(S-mean_S)*rsqrt(4*var_S+eps)*g_pred + b_pred, S = sum_h W2/(1+Ep*Ea).

typedef unsigned short ushort_t;
typedef __attribute__((ext_vector_type(8))) short short8;
typedef __attribute__((ext_vector_type(4))) float floatx4;

#define C2F 2.8853900817779268f  // 2*log2(e)
#define V_N 20000
#define NBLK 1250                // V_N / 16

__device__ __forceinline__ ushort_t f2bf(float f) {
    unsigned int u = __builtin_bit_cast(unsigned int, f);
    u += 0x7FFFu + ((u >> 16) & 1u);   // RNE
    return (ushort_t)(u >> 16);
}
__device__ __forceinline__ float exp2_fast(float x) { return __builtin_amdgcn_exp2f(x); }
__device__ __forceinline__ float rcp_fast(float x)  { return __builtin_amdgcn_rcpf(x); }

// ---------------------------------------------------------------------------
// prep: blocks 0..15 repack Wa / W1[D:] into B-frag order (validated R1-R8):
//   elem ((s*16+T)*64+l)*8+j = src[(s*32+(l>>4)*8+j)*256 + T*16+(l&15)]
// blocks 16..31: patient path, one block per b -> EpT[h*16+b]
// ---------------------------------------------------------------------------
__global__ __launch_bounds__(1024) void prep_kernel(
    const float* __restrict__ patient_emb, const float* __restrict__ Wp,
    const float* __restrict__ bp, const float* __restrict__ gp,
    const float* __restrict__ betap, const float* __restrict__ Wa,
    const float* __restrict__ W1, ushort_t* __restrict__ pWa,
    ushort_t* __restrict__ pW1b, float* __restrict__ EpT)
{
    const int blk = blockIdx.x;
    const int tid = threadIdx.x;
    __shared__ float peL[256];
    __shared__ float pL[256];
    __shared__ float part[4][256];
    __shared__ float red[8];

    if (blk < 16) {
        int slot = blk * 1024 + tid;        // 16384 slots = 2 matrices * 8192
        int matrix = slot >> 13;
        int rest = slot & 8191;
        int s = rest >> 10, T = (rest >> 6) & 15, l = rest & 63;
        const float* src = matrix ? (W1 + 256 * 256) : Wa;
        ushort_t* dst = matrix ? pW1b : pWa;
        int kbase = s * 32 + ((l >> 4) << 3);
        int nn = (T << 4) + (l & 15);
        short8 t;
        #pragma unroll
        for (int j = 0; j < 8; ++j)
            t[j] = (short)f2bf(src[(kbase + j) * 256 + nn]);
        *(short8*)(dst + rest * 8) = t;
        return;
    }

    const int b = blk - 16;
    const int j = tid & 255, pq = tid >> 8;   // 4-way K split
    if (tid < 256) peL[tid] = patient_emb[b * 256 + tid];
    __syncthreads();
    float a0 = 0.f;
    #pragma unroll 8
    for (int dd = 0; dd < 64; ++dd) {
        int d = pq * 64 + dd;
        a0 += peL[d] * Wp[d * 256 + j];
    }
    part[pq][j] = a0;
    __syncthreads();
    float x = 0.f;
    if (tid < 256) {
        x = part[0][j] + part[1][j] + part[2][j] + part[3][j] + bp[j];
        float s1 = x, s2 = x * x;
        #pragma unroll
        for (int off = 32; off; off >>= 1) {
            s1 += __shfl_xor(s1, off);
            s2 += __shfl_xor(s2, off);
        }
        int wv = tid >> 6;
        if ((tid & 63) == 0) { red[wv * 2] = s1; red[wv * 2 + 1] = s2; }
    }
    __syncthreads();
    if (tid < 256) {
        float s1 = red[0] + red[2] + red[4] + red[6];
        float s2 = red[1] + red[3] + red[5] + red[7];
        float mean = s1 * (1.f / 256.f);
        float var  = s2 * (1.f / 256.f) - mean * mean;
        float rstd = rsqrtf(var + 1e-5f);
        pL[tid] = (x - mean) * rstd * gp[tid] + betap[tid];
    }
    __syncthreads();
    float a2 = 0.f;
    #pragma unroll 8
    for (int dd = 0; dd < 64; ++dd) {
        int d = pq * 64 + dd;
        a2 += pL[d] * W1[d * 256 + j];   // W1[:D]
    }
    part[pq][j] = a2;
    __syncthreads();
    if (tid < 256)
        EpT[tid * 16 + b] = exp2_fast(
            C2F * (part[0][tid] + part[1][tid] + part[2][tid] + part[3][tid]));
}

// ---------------------------------------------------------------------------
// mega: 256 threads (4 waves), 16 v-rows. Wave w owns h/d cols [64w,64w+64).
// MFMA 16x16x32_bf16: A lane: A[m=lane&15][k=(lane>>4)*8+j]; C/D:
// D[(lane>>4)*4+r][lane&15]. A tile in LDS in frag order:
//   short8 slot (s*64 + q*16 + row)*8+j  <->  A[row][k=s*32+q*8+j]
// launch_bounds(256,3): ~170 unified VGPR/wave; (256,4) = 128 unified ->
// 64 arch + 64 acc -> spills (R4/R7 evidence). 3 waves/SIMD is the ceiling.
// ---------------------------------------------------------------------------
__global__ __launch_bounds__(256, 3) void mega_kernel(
    const float* __restrict__ atc4, const float* __restrict__ ba,
    const float* __restrict__ ga, const float* __restrict__ betaa,
    const float* __restrict__ b1, const float* __restrict__ W2,
    const ushort_t* __restrict__ pWa, const ushort_t* __restrict__ pW1b,
    const float* __restrict__ EpT, float* __restrict__ scores,
    float* __restrict__ s1g, float* __restrict__ s2g)
{
    __shared__ ushort_t AtileF[4096];      // 8 KB, frag order (8 s x 64 lane x 8)
    __shared__ float statsP[4][16][2];
    __shared__ float redbuf[16][4][17];    // [bg][w][v(+1 pad)] - batched tail

    const int tid = threadIdx.x;
    const int w = tid >> 6, lane = tid & 63;
    const int q = lane >> 4, n = lane & 15;
    const int v0 = blockIdx.x * 16;

    // ---- stage A tile (16 rows x 256 cols) straight into frag order ----
    {
        const int row = tid >> 4;
        const int kb = (tid & 15) * 16;
        const float* srcp = atc4 + (v0 + row) * 256 + kb;
        #pragma unroll
        for (int i = 0; i < 4; ++i) {
            int k = kb + i * 4;
            float4 f = *(const float4*)(srcp + i * 4);
            ushort4 usv = make_ushort4(f2bf(f.x), f2bf(f.y), f2bf(f.z), f2bf(f.w));
            int addr = (((k >> 5) * 64) + (((k >> 3) & 3) * 16) + row) * 8 + (k & 7);
            *(ushort4*)(AtileF + addr) = usv;
        }
    }
    __syncthreads();

    // ---- GEMM1: cols w*64 + ni*16 + n ----
    floatx4 acc[4];
    #pragma unroll
    for (int ni = 0; ni < 4; ++ni) acc[ni] = (floatx4){0.f, 0.f, 0.f, 0.f};
    #pragma unroll
    for (int s = 0; s < 8; ++s) {
        short8 a0 = ((const short8*)AtileF)[s * 64 + lane];
        #pragma unroll
        for (int ni = 0; ni < 4; ++ni) {
            short8 bfv = *(const short8*)(pWa + ((s * 16 + w * 4 + ni) * 64 + lane) * 8);
            acc[ni] = __builtin_amdgcn_mfma_f32_16x16x32_bf16(a0, bfv, acc[ni], 0, 0, 0);
        }
    }

    // ---- bias + partial LN stats (params inline from L1) ----
    float s1v[4] = {0, 0, 0, 0}, s2v[4] = {0, 0, 0, 0};
    #pragma unroll
    for (int ni = 0; ni < 4; ++ni) {
        float bav = ba[w * 64 + ni * 16 + n];
        #pragma unroll
        for (int r = 0; r < 4; ++r) {
            float x = acc[ni][r] + bav;
            acc[ni][r] = x;
            s1v[r] += x; s2v[r] += x * x;
        }
    }
    #pragma unroll
    for (int off = 1; off < 16; off <<= 1)
        #pragma unroll
        for (int r = 0; r < 4; ++r) {
            s1v[r] += __shfl_xor(s1v[r], off);
            s2v[r] += __shfl_xor(s2v[r], off);
        }
    if (n == 0) {
        #pragma unroll
        for (int r = 0; r < 4; ++r) {
            statsP[w][q * 4 + r][0] = s1v[r];
            statsP[w][q * 4 + r][1] = s2v[r];
        }
    }
    __syncthreads();

    // ---- per-lane final stats for this lane's 4 rows (no statsF phase) ----
    float meanv[4], rstdv[4];
    #pragma unroll
    for (int r = 0; r < 4; ++r) {
        int row = q * 4 + r;
        float m1 = statsP[0][row][0] + statsP[1][row][0] +
                   statsP[2][row][0] + statsP[3][row][0];
        float m2 = statsP[0][row][1] + statsP[1][row][1] +
                   statsP[2][row][1] + statsP[3][row][1];
        float mean = m1 * (1.f / 256.f);
        float var  = m2 * (1.f / 256.f) - mean * mean;
        meanv[r] = mean;
        rstdv[r] = rsqrtf(var + 1e-5f);
    }

    // ---- LN apply (ga/betaa inline); scatter bf16 back into AtileF ----
    #pragma unroll
    for (int ni = 0; ni < 4; ++ni) {
        float gav = ga[w * 64 + ni * 16 + n];
        float bev = betaa[w * 64 + ni * 16 + n];
        #pragma unroll
        for (int r = 0; r < 4; ++r) {
            int row = q * 4 + r;
            float xv = (acc[ni][r] - meanv[r]) * rstdv[r] * gav + bev;
            int addr = ((w * 2 + (ni >> 1)) * 64 +
                        ((ni & 1) * 2 + (n >> 3)) * 16 + row) * 8 + (n & 7);
            AtileF[addr] = f2bf(xv);
        }
    }
    __syncthreads();

    // ---- GEMM2 ----
    floatx4 acc2[4];
    #pragma unroll
    for (int ni = 0; ni < 4; ++ni) acc2[ni] = (floatx4){0.f, 0.f, 0.f, 0.f};
    #pragma unroll
    for (int s = 0; s < 8; ++s) {
        short8 a0 = ((const short8*)AtileF)[s * 64 + lane];
        #pragma unroll
        for (int ni = 0; ni < 4; ++ni) {
            short8 bfv = *(const short8*)(pW1b + ((s * 16 + w * 4 + ni) * 64 + lane) * 8);
            acc2[ni] = __builtin_amdgcn_mfma_f32_16x16x32_bf16(a0, bfv, acc2[ni], 0, 0, 0);
        }
    }

    // ---- Ea = exp2(C*(ah + b1)) IN PLACE (b1 inline) ----
    #pragma unroll
    for (int ni = 0; ni < 4; ++ni) {
        float b1v = C2F * b1[w * 64 + ni * 16 + n];
        #pragma unroll
        for (int r = 0; r < 4; ++r)
            acc2[ni][r] = exp2_fast(fmaf(C2F, acc2[ni][r], b1v));
    }

    // ---- contraction: 4 passes of 4 batch rows, Ep software-pipelined ----
    float w2c[4];
    #pragma unroll
    for (int ni = 0; ni < 4; ++ni) w2c[ni] = W2[w * 64 + ni * 16 + n];

    float4 epNext[4];
    #pragma unroll
    for (int ni = 0; ni < 4; ++ni)
        epNext[ni] = *(const float4*)(EpT + (w * 64 + ni * 16 + n) * 16);

    #pragma unroll 1
    for (int p = 0; p < 4; ++p) {
        float4 epCur[4];
        #pragma unroll
        for (int ni = 0; ni < 4; ++ni) epCur[ni] = epNext[ni];
        if (p < 3) {
            #pragma unroll
            for (int ni = 0; ni < 4; ++ni)
                epNext[ni] = *(const float4*)(EpT + (w * 64 + ni * 16 + n) * 16 +
                                              (p + 1) * 4);
        }
        float accs[4][4];
        #pragma unroll
        for (int bb = 0; bb < 4; ++bb)
            #pragma unroll
            for (int r = 0; r < 4; ++r) accs[bb][r] = 0.f;
        #pragma unroll
        for (int ni = 0; ni < 4; ++ni) {
            float ep[4] = {epCur[ni].x, epCur[ni].y, epCur[ni].z, epCur[ni].w};
            #pragma unroll
            for (int bb = 0; bb < 4; ++bb)
                #pragma unroll
                for (int r = 0; r < 4; ++r)
                    accs[bb][r] += w2c[ni] * rcp_fast(fmaf(ep[bb], acc2[ni][r], 1.f));
        }
        // butterfly reduce-scatter over 16 n-lanes: lane ends with b = p*4+(n&3)
        float t2v[2][4], t1[4];
        {
            int hb = n & 1;
            #pragma unroll
            for (int p2 = 0; p2 < 2; ++p2)
                #pragma unroll
                for (int r = 0; r < 4; ++r) {
                    float keep = hb ? accs[2 * p2 + 1][r] : accs[2 * p2][r];
                    float send = hb ? accs[2 * p2][r] : accs[2 * p2 + 1][r];
                    t2v[p2][r] = keep + __shfl_xor(send, 1);
                }
            hb = (n >> 1) & 1;
            #pragma unroll
            for (int r = 0; r < 4; ++r) {
                float keep = hb ? t2v[1][r] : t2v[0][r];
                float send = hb ? t2v[0][r] : t2v[1][r];
                t1[r] = keep + __shfl_xor(send, 2);
            }
            #pragma unroll
            for (int r = 0; r < 4; ++r) {
                t1[r] += __shfl_xor(t1[r], 4);
                t1[r] += __shfl_xor(t1[r], 8);
            }
        }
        if (n < 4) {
            #pragma unroll
            for (int r = 0; r < 4; ++r)
                redbuf[p * 4 + n][w][q * 4 + r] = t1[r];
        }
    }
    __syncthreads();   // ONE barrier for the whole batched tail
    {
        int bb = tid >> 4, v = tid & 15;   // all 256 threads: 16 b x 16 v
        float S = redbuf[bb][0][v] + redbuf[bb][1][v] +
                  redbuf[bb][2][v] + redbuf[bb][3][v];
        scores[bb * V_N + v0 + v] = S;
        float ls1 = S, ls2 = S * S;
        #pragma unroll
        for (int off = 1; off < 16; off <<= 1) {
            ls1 += __shfl_xor(ls1, off);
            ls2 += __shfl_xor(ls2, off);
        }
        if ((tid & 15) == 0) {
            s1g[bb * NBLK + blockIdx.x] = ls1;
            s2g[bb * NBLK + blockIdx.x] = ls2;
        }
    }
}

// ---------------------------------------------------------------------------
// final: grid (10 chunks, 16 b). Redundant cheap stats reduce per block, then
// out = -2*(S-mean)*rsqrt(4*var+eps)*g_pred + b_pred.
// ---------------------------------------------------------------------------
__global__ __launch_bounds__(256) void final_kernel(
    const float* __restrict__ scores, const float* __restrict__ s1g,
    const float* __restrict__ s2g, const float* __restrict__ g_pred,
    const float* __restrict__ b_pred, float* __restrict__ out)
{
    const int cx = blockIdx.x, b = blockIdx.y, tid = threadIdx.x;
    __shared__ float redL[8];
    float ls1 = 0.f, ls2 = 0.f;
    for (int i = tid; i < NBLK; i += 256) {
        ls1 += s1g[b * NBLK + i];
        ls2 += s2g[b * NBLK + i];
    }
    #pragma unroll
    for (int off = 32; off; off >>= 1) {
        ls1 += __shfl_xor(ls1, off);
        ls2 += __shfl_xor(ls2, off);
    }
    int w = tid >> 6;
    if ((tid & 63) == 0) { redL[w] = ls1; redL[4 + w] = ls2; }
    __syncthreads();
    float S1 = redL[0] + redL[1] + redL[2] + redL[3];
    float S2 = redL[4] + redL[5] + redL[6] + redL[7];
    float mean = S1 * (1.f / 20000.f);
    float var  = S2 * (1.f / 20000.f) - mean * mean;
    float k = -2.f * rsqrtf(4.f * var + 1e-5f);
    #pragma unroll
    for (int i = 0; i < 8; ++i) {
        int off = i * 256 + tid;
        if (off < 2000) {
            int v = cx * 2000 + off;
            float S = scores[b * V_N + v];
            out[b * V_N + v] = (S - mean) * k * g_pred[v] + b_pred[v];
        }
    }
}

extern "C" void kernel_launch(void* const* d_in, const int* in_sizes, int n_in,
                              void* d_out, int out_size, void* d_ws, size_t ws_size,
                              hipStream_t stream)
{
    const float* patient_emb = (const float*)d_in[0];
    const float* atc4        = (const float*)d_in[1];
    const float* Wp     = (const float*)d_in[2];
    const float* bp     = (const float*)d_in[3];
    const float* gp     = (const float*)d_in[4];
    const float* betap  = (const float*)d_in[5];
    const float* Wa     = (const float*)d_in[6];
    const float* ba     = (const float*)d_in[7];
    const float* ga     = (const float*)d_in[8];
    const float* betaa  = (const float*)d_in[9];
    const float* W1     = (const float*)d_in[10];
    const float* b1     = (const float*)d_in[11];
    const float* W2     = (const float*)d_in[12];
    // d_in[13] = b2: constant, cancels under the final LN
    const float* g_pred = (const float*)d_in[14];
    const float* b_pred = (const float*)d_in[15];

    char* ws = (char*)d_ws;
    float*    EpT    = (float*)(ws);                 //  16384 B
    ushort_t* pWa    = (ushort_t*)(ws + 16384);      // 131072 B
    ushort_t* pW1b   = (ushort_t*)(ws + 147456);     // 131072 B
    float*    scores = (float*)(ws + 278528);        // 1280000 B
    float*    s1g    = (float*)(ws + 1558528);       //  80000 B
    float*    s2g    = (float*)(ws + 1638528);       //  80000 B
    float*    out    = (float*)d_out;

    prep_kernel<<<32, 1024, 0, stream>>>(patient_emb, Wp, bp, gp, betap,
                                         Wa, W1, pWa, pW1b, EpT);
    mega_kernel<<<NBLK, 256, 0, stream>>>(atc4, ba, ga, betaa, b1, W2,
                                          pWa, pW1b, EpT, scores, s1g, s2g);
    final_kernel<<<dim3(10, 16), 256, 0, stream>>>(scores, s1g, s2g,
                                                   g_pred, b_pred, out);
}